// Round 13
// baseline (34.048 us; speedup 1.0000x reference)
//
#include <hip/hip_runtime.h>
#include <hip/hip_bf16.h>

#define LNUM 6
#define BATCH 131072

typedef __bf16 bf16x8 __attribute__((ext_vector_type(8)));
typedef float f32x16 __attribute__((ext_vector_type(16)));
typedef float f32x4  __attribute__((ext_vector_type(4)));

// ---------------- ws layout ----------------
// 36 W blocks, each 256x256 bf16 = 131072 B:
// [nh(2)][kk(16)][nti(4)][lane(64)][16B]
//   n = (nh*4+nti)*32 + (l&31), k = kk*16 + (l>>5)*8 + jj
#define WFRAG_BYTES 131072ul
#define W1B1_OFF 4718592ul   // 12 x (256 f32 W1row || 256 f32 B1)
#define BIAS_OFF 4743168ul   // 36 x 256 f32 (B2/B3/B4)
#define W5_OFF   4780032ul   // 12 x 272 f32 (W5 column || B5 || pad)
// Scalar-function tables (r29 win): each (net,layer) output is a 1-D
// function of the masked scalar z. NPT=2048 verified r30 (absmax exact).
#define NPT   2048
#define ZMIN  (-28.f)
#define ZH    (56.f / 2047.f)
#define ZINVH (2047.f / 56.f)
#define TABS_OFF 4793088ul   // 6 x 2048 f32: S_i(z) = tanh(o_s)
#define TABT_OFF 4842240ul   // 6 x 2048 f32: T_i(z) = o_t
#define WS_NEEDED 4891392ul

struct PtrPack { const float* p[21]; };

// -------- prep (merged, ILP; r31, theory-sound): blocks <288 pack
// W2/W3/W4 into MFMA fragment order, 4 elements/thread; blocks >=288
// build the small tables, 8 elements/thread. --------
__global__ void prep_all(PtrPack P, unsigned char* __restrict__ ws) {
    if (blockIdx.x < 288) {
#pragma unroll
        for (int r = 0; r < 4; ++r) {
            int t = blockIdx.x * 1024 + r * 256 + threadIdx.x;
            int blk = t >> 13;
            int e8  = t & 8191;
            int nh  = e8 >> 12;
            int kk  = (e8 >> 8) & 15;
            int nti = (e8 >> 6) & 3;
            int l   = e8 & 63;
            int nt = nh * 4 + nti;
            int n  = nt * 32 + (l & 31);
            int k0 = kk * 16 + (l >> 5) * 8;
            int net = blk / 18, rem = blk % 18;
            int i = rem / 3, g = rem % 3;
            const float* src = P.p[3 + g * 2 + net * 10] + i * 65536;
            bf16x8 v;
#pragma unroll
            for (int jj = 0; jj < 8; ++jj) v[jj] = (__bf16)src[(k0 + jj) * 256 + n];
            *(bf16x8*)(ws + (unsigned long)blk * WFRAG_BYTES + (unsigned)e8 * 16) = v;
        }
        return;
    }
#pragma unroll
    for (int r = 0; r < 8; ++r) {
        int t = (blockIdx.x - 288) * 2048 + r * 256 + threadIdx.x;
        if (t < 6144) {
            int idx = t >> 9, e = t & 511;
            int net = idx / 6, i = idx % 6;
            int j = (i & 1) ? 0 : 1;
            float v;
            if (e < 256) v = P.p[1 + net * 10][i * 512 + j * 256 + e];
            else         v = P.p[2 + net * 10][i * 256 + (e - 256)];
            ((float*)(ws + W1B1_OFF))[t] = v;
        } else if (t < 6144 + 9216) {
            int u = t - 6144;
            int idx = u >> 8, e = u & 255;
            int net = idx / 18, rem = idx % 18, i = rem / 3, g = rem % 3;
            ((float*)(ws + BIAS_OFF))[u] = P.p[4 + g * 2 + net * 10][i * 256 + e];
        } else if (t < 6144 + 9216 + 12 * 272) {
            int u = t - 6144 - 9216;
            int idx = u / 272, e = u % 272;
            int net = idx / 6, i = idx % 6;
            int ud = (i & 1) ? 1 : 0;
            float v = 0.f;
            if (e < 256)      v = P.p[9 + net * 10][i * 512 + e * 2 + ud];
            else if (e == 256) v = P.p[10 + net * 10][i * 2 + ud];
            ((float*)(ws + W5_OFF))[idx * 272 + e] = v;
        }
    }
}

// ---------------- table builder: 8-wave, RATIO-PRESERVING split ----------------
// r31's 8-wave used 32-col slices -> halved MFMA per ds_read (the r19/r24
// thin-wave failure family) and regressed. r32 splits by ROWS instead:
// wave (rh = wv>>2, wc = wv&3) owns rows [rh*64,+64) x cols [wc*64,+64):
// 4 MFMA per k-step from 2 aa + 2 wq loads = r21's exact 2:1 ratio,
// acc = 4 x f32x16 (64 AGPR). Both row-halves issue IDENTICAL W addresses
// (same block -> L2/L1 hits; total W traffic 4.6 MB, nothing like r25's
// cross-block duplication at main scale). 192 blocks x 512 thr -> 1
// block/CU, 2 waves/SIMD: the second wave hides the first's ds/L2/barrier
// stalls that r30's 1-wave/SIMD config fully exposed.
// Index maps re-derived from the r21-verified algebra (wv->wc, rt->2rh+rtl).
#define L_A   0       // 16*4096 = 65536
#define L_ZG  65536   // grid z [128]
#define L_RED 66048   // [8 waves][64 rows] f32 = 2048
#define L_TOT 68096

__device__ __forceinline__ unsigned pk2(float a, float b) {
    unsigned short ua = __builtin_bit_cast(unsigned short, (__bf16)a);
    unsigned short ub = __builtin_bit_cast(unsigned short, (__bf16)b);
    return (unsigned)ua | ((unsigned)ub << 16);
}

__global__ __launch_bounds__(512, 2) void tab_eval(
        const unsigned char* __restrict__ ws, float* __restrict__ tabS,
        float* __restrict__ tabT) {
    __shared__ __align__(16) unsigned char lds[L_TOT];
    const int tid = threadIdx.x;
    const int wv = tid >> 6, lane = tid & 63;
    const int li = lane & 31, hi = lane >> 5;
    const int rh = wv >> 2;                  // row half 0/1
    const int wc = wv & 3;                   // 64-col slice 0..3
    const int nn = blockIdx.x >> 4;          // net*6 + i
    const int tile = blockIdx.x & 15;
    float* zG  = (float*)(lds + L_ZG);
    float* red = (float*)(lds + L_RED);
    const float* w1b1_g = (const float*)(ws + W1B1_OFF);
    const float* bias_g = (const float*)(ws + BIAS_OFF);
    const float* w5_g   = (const float*)(ws + W5_OFF);

    const unsigned char* aaBase = lds + L_A + (unsigned)lane * 16;
    unsigned char* const stBase = lds + L_A + (unsigned)(li * 16 + hi * 8);

    if (tid < 128) zG[tid] = ZMIN + (float)(tile * 128 + tid) * ZH;
    __syncthreads();

    // relu -> bf16 pairs -> A-frag stores for this wave's 64x64 tile.
    // row = (2rh+rtl)*32+li, n = wc*64 + j2*32 + q*8 + hi*4 + c
    auto storeA = [&](const f32x16* a) {
#pragma unroll
        for (int rtl = 0; rtl < 2; ++rtl)
#pragma unroll
            for (int j2 = 0; j2 < 2; ++j2)
#pragma unroll
                for (int q = 0; q < 4; ++q) {
                    const f32x16& A = a[rtl * 2 + j2];
                    unsigned lo = pk2(fmaxf(A[4 * q + 0], 0.f), fmaxf(A[4 * q + 1], 0.f));
                    unsigned h2 = pk2(fmaxf(A[4 * q + 2], 0.f), fmaxf(A[4 * q + 3], 0.f));
                    const unsigned off = (unsigned)((wc * 4 + j2 * 2 + (q >> 1)) * 4096
                                                    + (rh * 2 + rtl) * 1024 + (q & 1) * 512);
                    *(uint2*)(stBase + off) = make_uint2(lo, h2);
                }
    };

    // ---- layer 1 as a single-k-step MFMA (r21-verified construction) ----
    {
        const float* w1 = w1b1_g + nn * 512;
        bf16x8 wf[2], af[2];
        const bf16x8 zr = {};
        if (hi == 0) {
#pragma unroll
            for (int f = 0; f < 2; ++f) {
                const int n = (wc * 2 + f) * 32 + li;
                const float W = w1[n], B = w1[256 + n];
                const __bf16 Wh = (__bf16)W;
                const __bf16 Wl = (__bf16)(W - (float)Wh);
                const __bf16 Bh = (__bf16)B;
                const __bf16 Bl = (__bf16)(B - (float)Bh);
                bf16x8 t = zr;
                t[0] = Wh; t[1] = Wl; t[2] = Wh; t[3] = Bh; t[4] = Bl;
                wf[f] = t;
            }
#pragma unroll
            for (int rtl = 0; rtl < 2; ++rtl) {
                const float z = zG[(rh * 2 + rtl) * 32 + li];
                const __bf16 zh = (__bf16)z;
                const __bf16 zl = (__bf16)(z - (float)zh);
                bf16x8 t2 = zr;
                t2[0] = zh; t2[1] = zh; t2[2] = zl;
                t2[3] = (__bf16)1.f; t2[4] = (__bf16)1.f;
                af[rtl] = t2;
            }
        } else {
            wf[0] = zr; wf[1] = zr;
            af[0] = zr; af[1] = zr;
        }
        f32x16 acc1[4];
#pragma unroll
        for (int u = 0; u < 4; ++u)
#pragma unroll
            for (int e = 0; e < 16; ++e) acc1[u][e] = 0.f;
#pragma unroll
        for (int rtl = 0; rtl < 2; ++rtl) {
            acc1[rtl * 2 + 0] = __builtin_amdgcn_mfma_f32_32x32x16_bf16(wf[0], af[rtl], acc1[rtl * 2 + 0], 0, 0, 0);
            acc1[rtl * 2 + 1] = __builtin_amdgcn_mfma_f32_32x32x16_bf16(wf[1], af[rtl], acc1[rtl * 2 + 1], 0, 0, 0);
        }
        storeA(acc1);
    }
    __syncthreads();

#pragma unroll 1
    for (int g = 0; g < 3; ++g) {
        const int blk = nn * 3 + g;
        // wave's 64-col W slice: nh = wc>>1, nti pair = (wc&1)*2 (+1024)
        const unsigned char* wbase = ws + (unsigned long)blk * WFRAG_BYTES
                + (unsigned)(wc >> 1) * 65536 + (unsigned)(wc & 1) * 2048
                + (unsigned)lane * 16;
        const float* biasl = bias_g + blk * 256 + wc * 64;
        const float* w5 = w5_g + nn * 272;

        f32x16 acc[4];   // [rtl*2+j2]: rows (2rh+rtl)*32.., n = wc*64+j2*32..
#pragma unroll
        for (int j2 = 0; j2 < 2; ++j2)
#pragma unroll
            for (int q = 0; q < 4; ++q) {
                f32x4 bb = *(const f32x4*)(biasl + j2 * 32 + q * 8 + hi * 4);
#pragma unroll
                for (int rtl = 0; rtl < 2; ++rtl) {
                    acc[rtl * 2 + j2][4 * q + 0] = bb[0];
                    acc[rtl * 2 + j2][4 * q + 1] = bb[1];
                    acc[rtl * 2 + j2][4 * q + 2] = bb[2];
                    acc[rtl * 2 + j2][4 * q + 3] = bb[3];
                }
            }
        bf16x8 wq[3][2];
#pragma unroll
        for (int p = 0; p < 3; ++p) {
            wq[p][0] = *(const bf16x8*)(wbase + p * 4096);
            wq[p][1] = *(const bf16x8*)(wbase + p * 4096 + 1024);
        }
        bf16x8 aa[2][2];
#pragma unroll
        for (int rtl = 0; rtl < 2; ++rtl)
            aa[0][rtl] = *(const bf16x8*)(aaBase + (rh * 2 + rtl) * 1024);
#pragma unroll
        for (int k = 0; k < 16; ++k) {
            const int cur = k & 1, nxt = cur ^ 1;
            if (k < 15) {
#pragma unroll
                for (int rtl = 0; rtl < 2; ++rtl)
                    aa[nxt][rtl] = *(const bf16x8*)(aaBase + (k + 1) * 4096
                                                    + (rh * 2 + rtl) * 1024);
            }
            __builtin_amdgcn_s_setprio(1);
#pragma unroll
            for (int rtl = 0; rtl < 2; ++rtl) {
                acc[rtl * 2 + 0] = __builtin_amdgcn_mfma_f32_32x32x16_bf16(wq[k % 3][0], aa[cur][rtl], acc[rtl * 2 + 0], 0, 0, 0);
                acc[rtl * 2 + 1] = __builtin_amdgcn_mfma_f32_32x32x16_bf16(wq[k % 3][1], aa[cur][rtl], acc[rtl * 2 + 1], 0, 0, 0);
            }
            __builtin_amdgcn_s_setprio(0);
            if (k < 13) {
                wq[k % 3][0] = *(const bf16x8*)(wbase + (k + 3) * 4096);
                wq[k % 3][1] = *(const bf16x8*)(wbase + (k + 3) * 4096 + 1024);
            }
        }
        __syncthreads();
        if (g < 2) {
            storeA(acc);
            __syncthreads();
        } else {
            // layer-5 dot over this wave's 64x64 tile; row-half-local reduce
            float part[2] = {0.f, 0.f};
#pragma unroll
            for (int j2 = 0; j2 < 2; ++j2)
#pragma unroll
                for (int q = 0; q < 4; ++q) {
                    f32x4 ww = *(const f32x4*)(w5 + wc * 64 + j2 * 32 + q * 8 + hi * 4);
#pragma unroll
                    for (int rtl = 0; rtl < 2; ++rtl)
#pragma unroll
                        for (int c = 0; c < 4; ++c)
                            part[rtl] += fmaxf(acc[rtl * 2 + j2][4 * q + c], 0.f) * ww[c];
                }
#pragma unroll
            for (int rtl = 0; rtl < 2; ++rtl) part[rtl] += __shfl_xor(part[rtl], 32);
            if (hi == 0) {
#pragma unroll
                for (int rtl = 0; rtl < 2; ++rtl)
                    red[wv * 64 + rtl * 32 + li] = part[rtl];
            }
            __syncthreads();
            if (tid < 128) {
                const int rhh = tid >> 6, loc = tid & 63;
                float o = w5[256];
#pragma unroll
                for (int w4 = 0; w4 < 4; ++w4)
                    o += red[(rhh * 4 + w4) * 64 + loc];
                const int pt = (nn % 6) * NPT + tile * 128 + tid;
                if (nn < 6) tabS[pt] = tanhf(o);   // s-net: store tanh(o_s)
                else        tabT[pt] = o;          // t-net: store o_t
            }
        }
    }
}

// ---------------- apply: 6 coupling layers via table lerp, 2 rows/thread ----------------
__global__ __launch_bounds__(256) void apply_flow(
        const float* __restrict__ x, const float* __restrict__ tabS,
        const float* __restrict__ tabT, float* __restrict__ out) {
    const int r = blockIdx.x * 256 + threadIdx.x;   // handles rows 2r, 2r+1
    const float4 xv = ((const float4*)x)[r];
    float zA0 = __logf(xv.x) - __logf(1.f - xv.x);
    float zB0 = __logf(xv.y) - __logf(1.f - xv.y);
    float zA1 = __logf(xv.z) - __logf(1.f - xv.z);
    float zB1 = __logf(xv.w) - __logf(1.f - xv.w);
    float ldt0 = 0.f, ldt1 = 0.f;
#pragma unroll
    for (int ii = 0; ii < LNUM; ++ii) {
        const int i = 5 - ii;
        const float* ts = tabS + i * NPT;
        const float* tt = tabT + i * NPT;
#pragma unroll
        for (int rr = 0; rr < 2; ++rr) {
            float& zA = rr ? zA1 : zA0;
            float& zB = rr ? zB1 : zB0;
            float& ldt = rr ? ldt1 : ldt0;
            const float zin = (i & 1) ? zA : zB;
            float u = (zin - ZMIN) * ZINVH;
            u = fminf(fmaxf(u, 0.f), (float)(NPT - 1) - 1e-3f);
            const int i0 = (int)u;
            const float fr = u - (float)i0;
            const float S = ts[i0] + (ts[i0 + 1] - ts[i0]) * fr;
            const float T = tt[i0] + (tt[i0 + 1] - tt[i0]) * fr;
            const float e = __expf(-S);
            if (i & 1) zB = (zB - T) * e;
            else       zA = (zA - T) * e;
            ldt -= S;
        }
    }
    ((float4*)out)[r] = make_float4(1.f / (1.f + __expf(-zA0)),
                                    1.f / (1.f + __expf(-zB0)),
                                    1.f / (1.f + __expf(-zA1)),
                                    1.f / (1.f + __expf(-zB1)));
    ((float2*)(out + 2 * BATCH))[r] = make_float2(ldt0, ldt1);
}

extern "C" void kernel_launch(void* const* d_in, const int* in_sizes, int n_in,
                              void* d_out, int out_size, void* d_ws, size_t ws_size,
                              hipStream_t stream) {
    if (ws_size < WS_NEEDED) return;
    PtrPack P;
    for (int k = 0; k < 21; ++k) P.p[k] = (const float*)d_in[k];
    unsigned char* ws = (unsigned char*)d_ws;
    float* tabS = (float*)(ws + TABS_OFF);
    float* tabT = (float*)(ws + TABT_OFF);
    prep_all<<<dim3(298), dim3(256), 0, stream>>>(P, ws);
    tab_eval<<<dim3(192), dim3(512), 0, stream>>>(ws, tabS, tabT);
    apply_flow<<<dim3(BATCH / 512), dim3(256), 0, stream>>>(
            (const float*)d_in[0], tabS, tabT, (float*)d_out);
}

// Round 15
// 30.707 us; speedup vs baseline: 1.1088x; 1.1088x over previous
//
#include <hip/hip_runtime.h>
#include <hip/hip_bf16.h>

#define LNUM 6
#define BATCH 131072

typedef __bf16 bf16x8 __attribute__((ext_vector_type(8)));
typedef float f32x16 __attribute__((ext_vector_type(16)));
typedef float f32x4  __attribute__((ext_vector_type(4)));

// ---------------- ws layout ----------------
// 36 W blocks, each 256x256 bf16 = 131072 B:
// [nh(2)][kk(16)][nti(4)][lane(64)][16B]
//   n = (nh*4+nti)*32 + (l&31), k = kk*16 + (l>>5)*8 + jj
#define WFRAG_BYTES 131072ul
#define W1B1_OFF 4718592ul   // 12 x (256 f32 W1row || 256 f32 B1)
#define BIAS_OFF 4743168ul   // 36 x 256 f32 (B2/B3/B4)
#define W5_OFF   4780032ul   // 12 x 272 f32 (W5 column || B5 || pad)
// Scalar-function tables (r29 win: each (net,layer) is a 1-D function of
// the masked scalar z). NPT=2048 verified r30 (absmax exact at 0.00390625).
// r34 = resubmit of r33 (exact r30-best revert, 29.8us) — r33's bench
// failed on an unresponsive container (infrastructure, no kernel signal).
#define NPT   2048
#define ZMIN  (-28.f)
#define ZH    (56.f / 2047.f)
#define ZINVH (2047.f / 56.f)
#define TABS_OFF 4793088ul   // 6 x 2048 f32: S_i(z) = tanh(o_s)
#define TABT_OFF 4842240ul   // 6 x 2048 f32: T_i(z) = o_t
#define WS_NEEDED 4891392ul

struct PtrPack { const float* p[21]; };

// -------- prep (merged): blocks <1152 pack W2/W3/W4 into MFMA fragment
// order (verified r4-r17); blocks >=1152 run the small-table path --------
__global__ void prep_all(PtrPack P, unsigned char* __restrict__ ws) {
    if (blockIdx.x < 1152) {
        int t = blockIdx.x * 256 + threadIdx.x;
        int blk = t >> 13;
        int e8  = t & 8191;
        int nh  = e8 >> 12;
        int kk  = (e8 >> 8) & 15;
        int nti = (e8 >> 6) & 3;
        int l   = e8 & 63;
        int nt = nh * 4 + nti;
        int n  = nt * 32 + (l & 31);
        int k0 = kk * 16 + (l >> 5) * 8;
        int net = blk / 18, rem = blk % 18;
        int i = rem / 3, g = rem % 3;
        const float* src = P.p[3 + g * 2 + net * 10] + i * 65536;
        bf16x8 v;
#pragma unroll
        for (int jj = 0; jj < 8; ++jj) v[jj] = (__bf16)src[(k0 + jj) * 256 + n];
        *(bf16x8*)(ws + (unsigned long)blk * WFRAG_BYTES + (unsigned)e8 * 16) = v;
        return;
    }
    int t = (blockIdx.x - 1152) * 256 + threadIdx.x;
    if (t < 6144) {
        int idx = t >> 9, e = t & 511;
        int net = idx / 6, i = idx % 6;
        int j = (i & 1) ? 0 : 1;
        float v;
        if (e < 256) v = P.p[1 + net * 10][i * 512 + j * 256 + e];
        else         v = P.p[2 + net * 10][i * 256 + (e - 256)];
        ((float*)(ws + W1B1_OFF))[t] = v;
    } else if (t < 6144 + 9216) {
        int u = t - 6144;
        int idx = u >> 8, e = u & 255;
        int net = idx / 18, rem = idx % 18, i = rem / 3, g = rem % 3;
        ((float*)(ws + BIAS_OFF))[u] = P.p[4 + g * 2 + net * 10][i * 256 + e];
    } else if (t < 6144 + 9216 + 12 * 272) {
        int u = t - 6144 - 9216;
        int idx = u / 272, e = u % 272;
        int net = idx / 6, i = idx % 6;
        int ud = (i & 1) ? 1 : 0;
        float v = 0.f;
        if (e < 256)      v = P.p[9 + net * 10][i * 512 + e * 2 + ud];
        else if (e == 256) v = P.p[10 + net * 10][i * 2 + ud];
        ((float*)(ws + W5_OFF))[idx * 272 + e] = v;
    }
}

// ---------------- table builder: r21's GEMM engine, one pass per block ----------------
// 192 blocks = 12 (net,layer) combos x 16 tiles of 128 grid points — fits
// in one resident generation (512 slots at 2 blocks/CU). Same bf16-MFMA
// math as the r21 main -> same error distribution as the 523us kernel.
#define L_A   0       // 16*4096 = 65536
#define L_ZG  65536   // grid z [128]
#define L_RED 67072   // [4 waves][128 rows] f32
#define L_TOT 69632

__device__ __forceinline__ unsigned pk2(float a, float b) {
    unsigned short ua = __builtin_bit_cast(unsigned short, (__bf16)a);
    unsigned short ub = __builtin_bit_cast(unsigned short, (__bf16)b);
    return (unsigned)ua | ((unsigned)ub << 16);
}

__global__ __launch_bounds__(256, 2) void tab_eval(
        const unsigned char* __restrict__ ws, float* __restrict__ tabS,
        float* __restrict__ tabT) {
    __shared__ __align__(16) unsigned char lds[L_TOT];
    const int tid = threadIdx.x;
    const int wv = tid >> 6, lane = tid & 63;
    const int li = lane & 31, hi = lane >> 5;
    const int nn = blockIdx.x >> 4;          // net*6 + i
    const int tile = blockIdx.x & 15;
    float* zG  = (float*)(lds + L_ZG);
    float* red = (float*)(lds + L_RED);
    const float* w1b1_g = (const float*)(ws + W1B1_OFF);
    const float* bias_g = (const float*)(ws + BIAS_OFF);
    const float* w5_g   = (const float*)(ws + W5_OFF);

    const unsigned char* aaBase = lds + L_A + (unsigned)lane * 16;
    unsigned char* const stBase = lds + L_A + (unsigned)(li * 16 + hi * 8);

    if (tid < 128) zG[tid] = ZMIN + (float)(tile * 128 + tid) * ZH;
    __syncthreads();

    auto storeA = [&](const f32x16* a) {
#pragma unroll
        for (int rt = 0; rt < 4; ++rt)
#pragma unroll
            for (int j2 = 0; j2 < 2; ++j2)
#pragma unroll
                for (int q = 0; q < 4; ++q) {
                    const f32x16& A = a[rt * 2 + j2];
                    unsigned lo = pk2(fmaxf(A[4 * q + 0], 0.f), fmaxf(A[4 * q + 1], 0.f));
                    unsigned h2 = pk2(fmaxf(A[4 * q + 2], 0.f), fmaxf(A[4 * q + 3], 0.f));
                    const unsigned off = (unsigned)((wv * 4 + j2 * 2 + (q >> 1)) * 4096
                                                    + rt * 1024 + (q & 1) * 512);
                    *(uint2*)(stBase + off) = make_uint2(lo, h2);
                }
    };

    // ---- layer 1 as a single-k-step MFMA (verified r21) ----
    {
        const float* w1 = w1b1_g + nn * 512;
        bf16x8 wf[2], af[4];
        const bf16x8 zr = {};
        if (hi == 0) {
#pragma unroll
            for (int f = 0; f < 2; ++f) {
                const int n = (wv * 2 + f) * 32 + li;
                const float W = w1[n], B = w1[256 + n];
                const __bf16 Wh = (__bf16)W;
                const __bf16 Wl = (__bf16)(W - (float)Wh);
                const __bf16 Bh = (__bf16)B;
                const __bf16 Bl = (__bf16)(B - (float)Bh);
                bf16x8 t = zr;
                t[0] = Wh; t[1] = Wl; t[2] = Wh; t[3] = Bh; t[4] = Bl;
                wf[f] = t;
            }
#pragma unroll
            for (int rt = 0; rt < 4; ++rt) {
                const float z = zG[rt * 32 + li];
                const __bf16 zh = (__bf16)z;
                const __bf16 zl = (__bf16)(z - (float)zh);
                bf16x8 t = zr;
                t[0] = zh; t[1] = zh; t[2] = zl;
                t[3] = (__bf16)1.f; t[4] = (__bf16)1.f;
                af[rt] = t;
            }
        } else {
            wf[0] = zr; wf[1] = zr;
            af[0] = zr; af[1] = zr; af[2] = zr; af[3] = zr;
        }
        f32x16 acc1[8];
#pragma unroll
        for (int u = 0; u < 8; ++u)
#pragma unroll
            for (int e = 0; e < 16; ++e) acc1[u][e] = 0.f;
#pragma unroll
        for (int rt = 0; rt < 4; ++rt) {
            acc1[rt * 2 + 0] = __builtin_amdgcn_mfma_f32_32x32x16_bf16(wf[0], af[rt], acc1[rt * 2 + 0], 0, 0, 0);
            acc1[rt * 2 + 1] = __builtin_amdgcn_mfma_f32_32x32x16_bf16(wf[1], af[rt], acc1[rt * 2 + 1], 0, 0, 0);
        }
        storeA(acc1);
    }
    __syncthreads();

#pragma unroll 1
    for (int g = 0; g < 3; ++g) {
        const int blk = nn * 3 + g;
        const unsigned char* wbase = ws + (unsigned long)blk * WFRAG_BYTES
                + (unsigned)(wv >> 1) * 65536 + (unsigned)(wv & 1) * 2048
                + (unsigned)lane * 16;
        const float* biasl = bias_g + blk * 256 + wv * 64;
        const float* w5 = w5_g + nn * 272;

        f32x16 acc[8];
#pragma unroll
        for (int j2 = 0; j2 < 2; ++j2)
#pragma unroll
            for (int q = 0; q < 4; ++q) {
                f32x4 bb = *(const f32x4*)(biasl + j2 * 32 + q * 8 + hi * 4);
#pragma unroll
                for (int rt = 0; rt < 4; ++rt) {
                    acc[rt * 2 + j2][4 * q + 0] = bb[0];
                    acc[rt * 2 + j2][4 * q + 1] = bb[1];
                    acc[rt * 2 + j2][4 * q + 2] = bb[2];
                    acc[rt * 2 + j2][4 * q + 3] = bb[3];
                }
            }
        bf16x8 wq[3][2];
#pragma unroll
        for (int p = 0; p < 3; ++p) {
            wq[p][0] = *(const bf16x8*)(wbase + p * 4096);
            wq[p][1] = *(const bf16x8*)(wbase + p * 4096 + 1024);
        }
        bf16x8 aa[2][4];
#pragma unroll
        for (int rt = 0; rt < 4; ++rt)
            aa[0][rt] = *(const bf16x8*)(aaBase + rt * 1024);
#pragma unroll
        for (int k = 0; k < 16; ++k) {
            const int cur = k & 1, nxt = cur ^ 1;
            if (k < 15) {
#pragma unroll
                for (int rt = 0; rt < 4; ++rt)
                    aa[nxt][rt] = *(const bf16x8*)(aaBase + (k + 1) * 4096 + rt * 1024);
            }
            __builtin_amdgcn_s_setprio(1);
#pragma unroll
            for (int rt = 0; rt < 4; ++rt) {
                acc[rt * 2 + 0] = __builtin_amdgcn_mfma_f32_32x32x16_bf16(wq[k % 3][0], aa[cur][rt], acc[rt * 2 + 0], 0, 0, 0);
                acc[rt * 2 + 1] = __builtin_amdgcn_mfma_f32_32x32x16_bf16(wq[k % 3][1], aa[cur][rt], acc[rt * 2 + 1], 0, 0, 0);
            }
            __builtin_amdgcn_s_setprio(0);
            if (k < 13) {
                wq[k % 3][0] = *(const bf16x8*)(wbase + (k + 3) * 4096);
                wq[k % 3][1] = *(const bf16x8*)(wbase + (k + 3) * 4096 + 1024);
            }
        }
        __syncthreads();
        if (g < 2) {
            storeA(acc);
            __syncthreads();
        } else {
            float part[4] = {0.f, 0.f, 0.f, 0.f};
#pragma unroll
            for (int j2 = 0; j2 < 2; ++j2)
#pragma unroll
                for (int q = 0; q < 4; ++q) {
                    f32x4 ww = *(const f32x4*)(w5 + wv * 64 + j2 * 32 + q * 8 + hi * 4);
#pragma unroll
                    for (int rt = 0; rt < 4; ++rt)
#pragma unroll
                        for (int c = 0; c < 4; ++c)
                            part[rt] += fmaxf(acc[rt * 2 + j2][4 * q + c], 0.f) * ww[c];
                }
#pragma unroll
            for (int rt = 0; rt < 4; ++rt) part[rt] += __shfl_xor(part[rt], 32);
            if (hi == 0) {
#pragma unroll
                for (int rt = 0; rt < 4; ++rt) red[wv * 128 + rt * 32 + li] = part[rt];
            }
            __syncthreads();
            if (tid < 128) {
                const float o = red[tid] + red[128 + tid] + red[256 + tid] + red[384 + tid]
                                + w5[256];
                const int pt = (nn % 6) * NPT + tile * 128 + tid;
                if (nn < 6) tabS[pt] = tanhf(o);   // s-net: store tanh(o_s)
                else        tabT[pt] = o;          // t-net: store o_t
            }
        }
    }
}

// ---------------- apply: 6 coupling layers via table lerp ----------------
__global__ __launch_bounds__(256) void apply_flow(
        const float* __restrict__ x, const float* __restrict__ tabS,
        const float* __restrict__ tabT, float* __restrict__ out) {
    const int r = blockIdx.x * 256 + threadIdx.x;
    const float2 xv = ((const float2*)x)[r];
    float zA = __logf(xv.x) - __logf(1.f - xv.x);
    float zB = __logf(xv.y) - __logf(1.f - xv.y);
    float ldt = 0.f;
#pragma unroll
    for (int ii = 0; ii < LNUM; ++ii) {
        const int i = 5 - ii;
        const float zin = (i & 1) ? zA : zB;
        float u = (zin - ZMIN) * ZINVH;
        u = fminf(fmaxf(u, 0.f), (float)(NPT - 1) - 1e-3f);
        const int i0 = (int)u;
        const float fr = u - (float)i0;
        const float* ts = tabS + i * NPT + i0;
        const float* tt = tabT + i * NPT + i0;
        const float S = ts[0] + (ts[1] - ts[0]) * fr;
        const float T = tt[0] + (tt[1] - tt[0]) * fr;
        const float e = __expf(-S);
        if (i & 1) zB = (zB - T) * e;
        else       zA = (zA - T) * e;
        ldt -= S;
    }
    ((float2*)out)[r] = make_float2(1.f / (1.f + __expf(-zA)),
                                    1.f / (1.f + __expf(-zB)));
    out[2 * BATCH + r] = ldt;
}

extern "C" void kernel_launch(void* const* d_in, const int* in_sizes, int n_in,
                              void* d_out, int out_size, void* d_ws, size_t ws_size,
                              hipStream_t stream) {
    if (ws_size < WS_NEEDED) return;
    PtrPack P;
    for (int k = 0; k < 21; ++k) P.p[k] = (const float*)d_in[k];
    unsigned char* ws = (unsigned char*)d_ws;
    float* tabS = (float*)(ws + TABS_OFF);
    float* tabT = (float*)(ws + TABT_OFF);
    prep_all<<<dim3(1225), dim3(256), 0, stream>>>(P, ws);
    tab_eval<<<dim3(192), dim3(256), 0, stream>>>(ws, tabS, tabT);
    apply_flow<<<dim3(BATCH / 256), dim3(256), 0, stream>>>(
            (const float*)d_in[0], tabS, tabT, (float*)d_out);
}